// Round 7
// baseline (161.455 us; speedup 1.0000x reference)
//
#include <hip/hip_runtime.h>
#include <math.h>

#define N 3072
#define FEAT 128
#define NE 24576
#define PSTRIDE 64         // per-node pair-slot row stride
#define EPT 24             // edges per prop thread (NE/1024)
#define NBLK 256           // mega-kernel blocks (1/CU, co-resident)
#define DOTB 768           // k_init: N/4 blocks of 4 waves for dots
#define OUTZ4 2459136      // d_out float4 count = 39,346,176/16
#define OUTZB 2402         // ceil(OUTZ4/1024)
#define WSZ4 1540          // zero region float4s = (64 + 2*N*4)/16
#define WSZB 2

// Wave-aggregated atomic add: group lanes by key, one atomicAdd per distinct
// key per wave. All 64 lanes must reach this call.
__device__ __forceinline__ void wave_agg_add(bool valid, int key, float val,
                                             float* base, int stride, int off) {
    int lane = threadIdx.x & 63;
    unsigned long long active = __ballot(valid ? 1 : 0);
    while (active) {
        int leader = __ffsll(active) - 1;
        int lkey = __shfl(key, leader);
        bool mine = valid && (key == lkey);
        unsigned long long grp = __ballot(mine ? 1 : 0);
        float v = mine ? val : 0.0f;
        #pragma unroll
        for (int o = 32; o; o >>= 1) v += __shfl_xor(v, o);
        if (lane == leader)
            atomicAdd(&base[(size_t)lkey * stride + off], v);
        active &= ~grp;
    }
}

// Device-scope sense barrier. bar[0]=arrive count, bar[1]=generation.
__device__ __forceinline__ void gsync(int* bar, int* lgen) {
    __syncthreads();
    if (threadIdx.x == 0) {
        __threadfence();
        int g = ++(*lgen);
        if (atomicAdd(&bar[0], 1) == (int)gridDim.x - 1) {
            __hip_atomic_store(&bar[0], 0, __ATOMIC_RELAXED, __HIP_MEMORY_SCOPE_AGENT);
            __threadfence();
            atomicAdd(&bar[1], 1);
        } else {
            while (__hip_atomic_load(&bar[1], __ATOMIC_RELAXED,
                                     __HIP_MEMORY_SCOPE_AGENT) < g)
                __builtin_amdgcn_s_sleep(8);
        }
        __threadfence();
    } else {
        ++(*lgen);
    }
    __syncthreads();
}

// blocks [0,DOTB): a[i]=x[i].w[0:128], c[i]=x[i].w[128:256] (wave per node)
// blocks [DOTB,+OUTZB): zero d_out; blocks [DOTB+OUTZB,+WSZB): zero [bar|pcnt|notsing]
__global__ void k_init(const float* __restrict__ x, const float* __restrict__ w,
                       float* __restrict__ a, float* __restrict__ c,
                       float4* __restrict__ zout, float4* __restrict__ zws) {
    int b = blockIdx.x, t = threadIdx.x;
    if (b < DOTB) {
        int node = b * 4 + (t >> 6);
        int lane = t & 63;
        const float* xi = x + node * FEAT;
        float pa = xi[lane] * w[lane] + xi[lane + 64] * w[lane + 64];
        float pc = xi[lane] * w[FEAT + lane] + xi[lane + 64] * w[FEAT + lane + 64];
        for (int off = 32; off; off >>= 1) {
            pa += __shfl_down(pa, off);
            pc += __shfl_down(pc, off);
        }
        if (lane == 0) { a[node] = pa; c[node] = pc; }
    } else if (b < DOTB + OUTZB) {
        float4 z = {0.f, 0.f, 0.f, 0.f};
        int base = (b - DOTB) * 1024;
        #pragma unroll
        for (int k = 0; k < 4; ++k) {
            int idx = base + k * 256 + t;
            if (idx < OUTZ4) zout[idx] = z;
        }
    } else {
        float4 z = {0.f, 0.f, 0.f, 0.f};
        int base = (b - DOTB - OUTZB) * 1024;
        #pragma unroll
        for (int k = 0; k < 4; ++k) {
            int idx = base + k * 256 + t;
            if (idx < WSZ4) zws[idx] = z;
        }
    }
}

// Single persistent kernel (256 blocks x 1024, all co-resident):
// phase 1: edge scoring + row append; phase 2: prop (block 0) || gather;
// phase 3: X-reduce + A-count.
__global__ void __launch_bounds__(1024, 4)
k_mega(const int* __restrict__ ei, const float* __restrict__ x,
       const float* __restrict__ a, const float* __restrict__ c,
       const float* __restrict__ bb, int* __restrict__ bar,
       int* __restrict__ pcnt, int* __restrict__ notsingle,
       unsigned* __restrict__ ep, unsigned long long* __restrict__ qmask,
       float* __restrict__ y, unsigned long long* __restrict__ ptab,
       int* __restrict__ cluster, float* __restrict__ Xnew,
       float* __restrict__ Anew, float* __restrict__ out_cluster) {
    __shared__ int lab[N];
    __shared__ int ssum[1024];
    __shared__ unsigned short rk[N];
    __shared__ int sh_p[16 * 64];
    __shared__ int flag;
    int t = threadIdx.x, blk = blockIdx.x;
    int wv = t >> 6, lane = t & 63;
    int lgen = 0;

    // ---- phase 1: 96 edges per block (NE = 256*96 exactly) ----
    if (t < 96) {
        int s = blk * 96 + t;
        int u = ei[s], v = ei[NE + s];
        unsigned wpk = (unsigned)u | ((unsigned)v << 12);
        if (u != v) {
            float b = bb[0];
            float su = a[u] + c[v] + b;    // S[u,v]; A_c[u,v]
            float sv = a[v] + c[u] + b;    // S[v,u]; A_c[v,u]
            unsigned fu = (su > 0.f) ? 1u : 0u;
            unsigned fv = (sv > 0.f) ? 1u : 0u;
            wpk |= (fu << 24) | (fv << 25);
            if (fu | fv) { notsingle[u] = 1; notsingle[v] = 1; }
            // append (e(u->v), p=u) to row q=v ; duplicates deduped at gather
            float eu = tanhf(su);
            int sl = atomicAdd(&pcnt[v], 1);
            if (sl < PSTRIDE)
                ptab[(size_t)v * PSTRIDE + sl] =
                    ((unsigned long long)__float_as_uint(eu) << 32) | (unsigned)u;
            float ev2 = tanhf(sv);
            sl = atomicAdd(&pcnt[u], 1);
            if (sl < PSTRIDE)
                ptab[(size_t)u * PSTRIDE + sl] =
                    ((unsigned long long)__float_as_uint(ev2) << 32) | (unsigned)v;
        }
        ep[s] = wpk;
    }
    gsync(bar, &lgen);

    // ---- phase 2: block 0 = label fixpoint + rank; others = dedup + gather ----
    if (blk == 0) {
        unsigned er[EPT];
        #pragma unroll
        for (int j = 0; j < EPT; ++j) er[j] = ep[t + j * 1024];
        for (int i = t; i < N; i += 1024) lab[i] = i;
        for (;;) {
            __syncthreads();
            if (t == 0) flag = 0;
            __syncthreads();
            #pragma unroll
            for (int j = 0; j < EPT; ++j) {
                unsigned wpk = er[j];
                int u = wpk & 0xFFF, v = (wpk >> 12) & 0xFFF;
                if (wpk & (1u << 24)) {
                    int lv = lab[v];
                    if (lv < lab[u]) { atomicMin(&lab[u], lv); flag = 1; }
                }
                if (wpk & (1u << 25)) {
                    int lu = lab[u];
                    if (lu < lab[v]) { atomicMin(&lab[v], lu); flag = 1; }
                }
            }
            for (int i = t; i < N; i += 1024) {
                int m = lab[i];
                int mm = lab[m];
                while (mm < m) { m = mm; mm = lab[m]; }
                if (m < lab[i]) { atomicMin(&lab[i], m); flag = 1; }
            }
            __syncthreads();
            if (!flag) break;
        }
        // rank roots: cumsum(lab[i]==i)-1; cluster[j]=rank[lab[j]]
        int i0 = 3 * t;
        int r0 = (lab[i0] == i0);
        int r1 = (lab[i0 + 1] == i0 + 1);
        int r2 = (lab[i0 + 2] == i0 + 2);
        int s = r0 + r1 + r2;
        ssum[t] = s;
        __syncthreads();
        for (int off = 1; off < 1024; off <<= 1) {
            int val = (t >= off) ? ssum[t - off] : 0;
            __syncthreads();
            ssum[t] += val;
            __syncthreads();
        }
        int run = ssum[t] - s;
        run += r0; rk[i0]     = (unsigned short)(run - 1);
        run += r1; rk[i0 + 1] = (unsigned short)(run - 1);
        run += r2; rk[i0 + 2] = (unsigned short)(run - 1);
        __syncthreads();
        for (int j = t; j < N; j += 1024) {
            int cl = rk[lab[j]];
            cluster[j] = cl;
            out_cluster[j] = (float)cl;
        }
    } else {
        int q = (blk - 1) * 16 + wv;
        if (q < N) {
            int cnt = pcnt[q]; if (cnt > PSTRIDE) cnt = PSTRIDE;
            const unsigned long long* row = ptab + (size_t)q * PSTRIDE;
            int myp = -1 - lane;      // unique negative: never matches
            float mye = 0.f;
            if (lane < cnt) {
                unsigned long long s = row[lane];
                myp = (int)(s & 0xFFFFFFFFu);
                mye = __uint_as_float((unsigned)(s >> 32));
            }
            sh_p[wv * 64 + lane] = myp;
            bool dup = false;
            for (int j = 0; j < lane && !dup; ++j)
                dup = (sh_p[wv * 64 + j] == myp);
            bool valid = (lane < cnt) && !dup;
            unsigned long long m = __ballot(valid ? 1 : 0);
            if (lane == 0) qmask[q] = m;
            float acc0 = 0.f, acc1 = 0.f;
            for (int j = 0; j < cnt; ++j) {
                if (!((m >> j) & 1ull)) continue;
                int p = __shfl(myp, j);
                float e = __shfl(mye, j);
                const float* xp = x + p * FEAT;
                acc0 += e * xp[lane];
                acc1 += e * xp[lane + 64];
            }
            if (!notsingle[q]) {
                const float* xq = x + q * FEAT;
                acc0 += xq[lane];
                acc1 += xq[lane + 64];
            }
            float* yq = y + q * FEAT;
            yq[lane] = acc0;
            yq[lane + 64] = acc1;
        }
    }
    gsync(bar, &lgen);

    // ---- phase 3: gwaves [0,6144): X-reduce; [6144,9216): A-count ----
    for (int gw = blk * 16 + wv; gw < 9216; gw += NBLK * 16) {
        if (gw < 6144) {
            int f = gw & (FEAT - 1);
            int chunk = gw >> 7;
            int q = chunk * 64 + lane;
            wave_agg_add(true, cluster[q], y[q * FEAT + f], Xnew, FEAT, f);
        } else {
            int q = gw - 6144;
            int cnt = pcnt[q]; if (cnt > PSTRIDE) cnt = PSTRIDE;
            unsigned long long m = qmask[q];
            bool valid = (lane < cnt) && ((m >> lane) & 1ull);
            int p = 0;
            if (valid) p = (int)(ptab[(size_t)q * PSTRIDE + lane] & 0xFFFFFFFFu);
            int cq = cluster[q];
            int cp = valid ? cluster[p] : 0;
            valid = valid && (cp != cq);
            wave_agg_add(valid, cp * N + cq, 1.0f, Anew, 1, 0);
        }
    }
}

extern "C" void kernel_launch(void* const* d_in, const int* in_sizes, int n_in,
                              void* d_out, int out_size, void* d_ws, size_t ws_size,
                              hipStream_t stream) {
    const float* x  = (const float*)d_in[0];
    const int*   ei = (const int*)d_in[1];
    const float* w  = (const float*)d_in[3];
    const float* bb = (const float*)d_in[4];

    // workspace layout — zero region FIRST: [bar(64B) | pcnt | notsing]
    char* ws = (char*)d_ws;
    size_t off = 0;
    int* bar      = (int*)(ws + off);      off += 64;
    int* pcnt     = (int*)(ws + off);      off += (size_t)N * 4;
    int* notsing  = (int*)(ws + off);      off += (size_t)N * 4;
    // zero region total = 24,640 B = WSZ4 * 16
    float* a      = (float*)(ws + off);    off += (size_t)N * 4;
    float* c      = (float*)(ws + off);    off += (size_t)N * 4;
    int* cluster  = (int*)(ws + off);      off += (size_t)N * 4;
    unsigned* ep  = (unsigned*)(ws + off); off += (size_t)NE * 4;
    unsigned long long* qmask = (unsigned long long*)(ws + off); off += (size_t)N * 8;
    float* y      = (float*)(ws + off);    off += (size_t)N * FEAT * 4;
    unsigned long long* ptab = (unsigned long long*)(ws + off); off += (size_t)N * PSTRIDE * 8;

    // output layout (all float32)
    float* Xnew        = (float*)d_out;                 // N*FEAT
    float* Anew        = Xnew + (size_t)N * FEAT;       // N*N
    float* out_cluster = Anew + (size_t)N * N + N;      // after new_batch (zeros)

    k_init<<<DOTB + OUTZB + WSZB, 256, 0, stream>>>(x, w, a, c,
                                                    (float4*)d_out, (float4*)ws);
    k_mega<<<NBLK, 1024, 0, stream>>>(ei, x, a, c, bb, bar, pcnt, notsing,
                                      ep, qmask, y, ptab, cluster,
                                      Xnew, Anew, out_cluster);
}

// Round 8
// 146.203 us; speedup vs baseline: 1.1043x; 1.1043x over previous
//
#include <hip/hip_runtime.h>
#include <math.h>

#define N 3072
#define FEAT 128
#define NE 24576
#define PSTRIDE 64         // per-node pair-slot row stride
#define EPT 24             // edges per prop thread (NE/1024)
#define DOTB 768           // k_init dot blocks (4 nodes each)
#define OUTZ4 2458368      // f4 count of [Xnew|Anew|new_batch] = 9,833,472 floats
#define ZB3 608            // zero blocks in k_prop_gather (4096 f4 each, bounds-checked)
#define GATB 192           // gather blocks (16 q rows each)

// Wave-aggregated atomic add: group lanes by key, one atomicAdd per distinct
// key per wave. All 64 lanes must reach this call.
__device__ __forceinline__ void wave_agg_add(bool valid, int key, float val,
                                             float* base, int stride, int off) {
    int lane = threadIdx.x & 63;
    unsigned long long active = __ballot(valid ? 1 : 0);
    while (active) {
        int leader = __ffsll(active) - 1;
        int lkey = __shfl(key, leader);
        bool mine = valid && (key == lkey);
        unsigned long long grp = __ballot(mine ? 1 : 0);
        float v = mine ? val : 0.0f;
        #pragma unroll
        for (int o = 32; o; o >>= 1) v += __shfl_xor(v, o);
        if (lane == leader)
            atomicAdd(&base[(size_t)lkey * stride + off], v);
        active &= ~grp;
    }
}

// blocks [0,DOTB): a[i]=x[i].w[0:128], c[i]=x[i].w[128:256] (wave per node)
// block DOTB: zero [pcnt|notsing] (1536 f4)
__global__ void k_init(const float* __restrict__ x, const float* __restrict__ w,
                       float* __restrict__ a, float* __restrict__ c,
                       float4* __restrict__ zws) {
    int b = blockIdx.x, t = threadIdx.x;
    if (b < DOTB) {
        int node = b * 4 + (t >> 6);
        int lane = t & 63;
        const float* xi = x + node * FEAT;
        float pa = xi[lane] * w[lane] + xi[lane + 64] * w[lane + 64];
        float pc = xi[lane] * w[FEAT + lane] + xi[lane + 64] * w[FEAT + lane + 64];
        for (int off = 32; off; off >>= 1) {
            pa += __shfl_down(pa, off);
            pc += __shfl_down(pc, off);
        }
        if (lane == 0) { a[node] = pa; c[node] = pc; }
    } else {
        float4 z = {0.f, 0.f, 0.f, 0.f};
        #pragma unroll
        for (int k = 0; k < 6; ++k) zws[k * 256 + t] = z;
    }
}

// score both directions, pack ep, mark not-single, append (e,p) to q's row
__global__ void k_edge_pairs(const int* __restrict__ ei, const float* __restrict__ a,
                             const float* __restrict__ c, const float* __restrict__ bb,
                             unsigned* __restrict__ ep, int* __restrict__ notsingle,
                             int* __restrict__ pcnt, unsigned long long* __restrict__ ptab) {
    int t = blockIdx.x * blockDim.x + threadIdx.x;
    if (t >= NE) return;
    int u = ei[t], v = ei[NE + t];
    unsigned wpk = (unsigned)u | ((unsigned)v << 12);
    if (u != v) {
        float b = bb[0];
        float su = a[u] + c[v] + b;    // S[u,v]; A_c[u,v]
        float sv = a[v] + c[u] + b;    // S[v,u]; A_c[v,u]
        unsigned fu = (su > 0.f) ? 1u : 0u;
        unsigned fv = (sv > 0.f) ? 1u : 0u;
        wpk |= (fu << 24) | (fv << 25);
        if (fu | fv) { notsingle[u] = 1; notsingle[v] = 1; }
        float eu = tanhf(su);
        int sl = atomicAdd(&pcnt[v], 1);
        if (sl < PSTRIDE)
            ptab[(size_t)v * PSTRIDE + sl] =
                ((unsigned long long)__float_as_uint(eu) << 32) | (unsigned)u;
        float ev2 = tanhf(sv);
        sl = atomicAdd(&pcnt[u], 1);
        if (sl < PSTRIDE)
            ptab[(size_t)u * PSTRIDE + sl] =
                ((unsigned long long)__float_as_uint(ev2) << 32) | (unsigned)v;
    }
    ep[t] = wpk;
}

// block 0: LDS label fixpoint (terminal-0 active-pair pruning) + rank + cluster
// blocks 1..GATB: dedup + gather y rows; blocks GATB+1..: zero [Xnew|Anew|new_batch]
__global__ void __launch_bounds__(1024)
k_prop_gather(const unsigned* __restrict__ ep, const float* __restrict__ x,
              const int* __restrict__ pcnt, const unsigned long long* __restrict__ ptab,
              const int* __restrict__ notsingle, float* __restrict__ y,
              unsigned long long* __restrict__ qmask, int* __restrict__ cluster,
              float* __restrict__ out_cluster, float4* __restrict__ zout) {
    __shared__ int lab[N];
    __shared__ int ssum[1024];
    __shared__ unsigned short rk[N];
    __shared__ int sh_p[16 * 64];
    __shared__ int flag;
    int t = threadIdx.x, blk = blockIdx.x;
    int wv = t >> 6, lane = t & 63;
    if (blk == 0) {
        unsigned er[EPT];
        unsigned act = 0;
        #pragma unroll
        for (int j = 0; j < EPT; ++j) {
            er[j] = ep[t + j * 1024];
            if (er[j] & 0x3000000u) act |= (1u << j);
        }
        for (int i = t; i < N; i += 1024) lab[i] = i;
        for (;;) {
            __syncthreads();
            if (t == 0) flag = 0;
            __syncthreads();
            unsigned rem = act;
            while (rem) {
                int j = __ffs(rem) - 1;
                rem &= rem - 1;
                unsigned wpk = er[j];
                int u = wpk & 0xFFF, v = (wpk >> 12) & 0xFFF;
                int lu = lab[u], lv = lab[v];
                if ((lu | lv) == 0) { act &= ~(1u << j); continue; }  // terminal
                if ((wpk & (1u << 24)) && lv < lu) { atomicMin(&lab[u], lv); flag = 1; }
                if ((wpk & (1u << 25)) && lu < lv) { atomicMin(&lab[v], lu); flag = 1; }
            }
            for (int i = t; i < N; i += 1024) {
                int m = lab[i];
                if (m == 0) continue;
                int mm = lab[m];
                while (mm < m) { m = mm; mm = lab[m]; }
                if (m < lab[i]) { atomicMin(&lab[i], m); flag = 1; }
            }
            __syncthreads();
            if (!flag) break;
        }
        // rank roots: cumsum(lab[i]==i)-1; cluster[j]=rank[lab[j]]
        int i0 = 3 * t;
        int r0 = (lab[i0] == i0);
        int r1 = (lab[i0 + 1] == i0 + 1);
        int r2 = (lab[i0 + 2] == i0 + 2);
        int s = r0 + r1 + r2;
        ssum[t] = s;
        __syncthreads();
        for (int off = 1; off < 1024; off <<= 1) {
            int val = (t >= off) ? ssum[t - off] : 0;
            __syncthreads();
            ssum[t] += val;
            __syncthreads();
        }
        int run = ssum[t] - s;
        run += r0; rk[i0]     = (unsigned short)(run - 1);
        run += r1; rk[i0 + 1] = (unsigned short)(run - 1);
        run += r2; rk[i0 + 2] = (unsigned short)(run - 1);
        __syncthreads();
        for (int j = t; j < N; j += 1024) {
            int cl = rk[lab[j]];
            cluster[j] = cl;
            out_cluster[j] = (float)cl;
        }
    } else if (blk <= GATB) {
        int q = (blk - 1) * 16 + wv;
        int cnt = pcnt[q]; if (cnt > PSTRIDE) cnt = PSTRIDE;
        const unsigned long long* row = ptab + (size_t)q * PSTRIDE;
        int myp = -1 - lane;      // unique negative: never matches a real p
        float mye = 0.f;
        if (lane < cnt) {
            unsigned long long s = row[lane];
            myp = (int)(s & 0xFFFFFFFFu);
            mye = __uint_as_float((unsigned)(s >> 32));
        }
        sh_p[wv * 64 + lane] = myp;
        bool dup = false;
        for (int j = 0; j < lane && !dup; ++j)
            dup = (sh_p[wv * 64 + j] == myp);
        bool valid = (lane < cnt) && !dup;
        unsigned long long m = __ballot(valid ? 1 : 0);
        if (lane == 0) qmask[q] = m;
        float acc0 = 0.f, acc1 = 0.f;
        for (int j = 0; j < cnt; ++j) {
            if (!((m >> j) & 1ull)) continue;
            int p = __shfl(myp, j);
            float e = __shfl(mye, j);
            const float* xp = x + p * FEAT;
            acc0 += e * xp[lane];
            acc1 += e * xp[lane + 64];
        }
        if (!notsingle[q]) {
            const float* xq = x + q * FEAT;
            acc0 += xq[lane];
            acc1 += xq[lane + 64];
        }
        float* yq = y + q * FEAT;
        yq[lane] = acc0;
        yq[lane + 64] = acc1;
    } else {
        float4 z = {0.f, 0.f, 0.f, 0.f};
        int base = (blk - GATB - 1) * 4096;
        #pragma unroll
        for (int k = 0; k < 4; ++k) {
            int idx = base + k * 1024 + t;
            if (idx < OUTZ4) zout[idx] = z;
        }
    }
}

// gwaves [0,6144): X_new[cluster[q]][f] += y[q][f] (wave-aggregated)
// gwaves [6144,9216): A_new counts from ptab/qmask, diagonal keys skipped
__global__ void k_reduce_anew(const float* __restrict__ y, const int* __restrict__ cluster,
                              const int* __restrict__ pcnt,
                              const unsigned long long* __restrict__ ptab,
                              const unsigned long long* __restrict__ qmask,
                              float* __restrict__ Xnew, float* __restrict__ Anew) {
    int gid = blockIdx.x * blockDim.x + threadIdx.x;
    int wid = gid >> 6, lane = gid & 63;
    if (wid < 6144) {
        int f = wid & (FEAT - 1);
        int chunk = wid >> 7;
        int q = chunk * 64 + lane;
        wave_agg_add(true, cluster[q], y[q * FEAT + f], Xnew, FEAT, f);
    } else {
        int q = wid - 6144;
        int cnt = pcnt[q]; if (cnt > PSTRIDE) cnt = PSTRIDE;
        unsigned long long m = qmask[q];
        bool valid = (lane < cnt) && ((m >> lane) & 1ull);
        int p = 0;
        if (valid) p = (int)(ptab[(size_t)q * PSTRIDE + lane] & 0xFFFFFFFFu);
        int cq = cluster[q];
        int cp = valid ? cluster[p] : 0;
        valid = valid && (cp != cq);
        wave_agg_add(valid, cp * N + cq, 1.0f, Anew, 1, 0);
    }
}

extern "C" void kernel_launch(void* const* d_in, const int* in_sizes, int n_in,
                              void* d_out, int out_size, void* d_ws, size_t ws_size,
                              hipStream_t stream) {
    const float* x  = (const float*)d_in[0];
    const int*   ei = (const int*)d_in[1];
    const float* w  = (const float*)d_in[3];
    const float* bb = (const float*)d_in[4];

    // workspace layout — zero region FIRST: [pcnt | notsing] (24,576 B)
    char* ws = (char*)d_ws;
    size_t off = 0;
    int* pcnt     = (int*)(ws + off);      off += (size_t)N * 4;
    int* notsing  = (int*)(ws + off);      off += (size_t)N * 4;
    float* a      = (float*)(ws + off);    off += (size_t)N * 4;
    float* c      = (float*)(ws + off);    off += (size_t)N * 4;
    int* cluster  = (int*)(ws + off);      off += (size_t)N * 4;
    unsigned* ep  = (unsigned*)(ws + off); off += (size_t)NE * 4;
    unsigned long long* qmask = (unsigned long long*)(ws + off); off += (size_t)N * 8;
    float* y      = (float*)(ws + off);    off += (size_t)N * FEAT * 4;
    unsigned long long* ptab = (unsigned long long*)(ws + off); off += (size_t)N * PSTRIDE * 8;

    // output layout (all float32)
    float* Xnew        = (float*)d_out;                 // N*FEAT
    float* Anew        = Xnew + (size_t)N * FEAT;       // N*N
    float* out_cluster = Anew + (size_t)N * N + N;      // after new_batch (zeros)

    k_init<<<DOTB + 1, 256, 0, stream>>>(x, w, a, c, (float4*)ws);
    k_edge_pairs<<<NE / 256, 256, 0, stream>>>(ei, a, c, bb, ep, notsing, pcnt, ptab);
    k_prop_gather<<<1 + GATB + ZB3, 1024, 0, stream>>>(ep, x, pcnt, ptab, notsing, y,
                                                       qmask, cluster, out_cluster,
                                                       (float4*)d_out);
    k_reduce_anew<<<(9216 * 64) / 1024, 1024, 0, stream>>>(y, cluster, pcnt, ptab,
                                                           qmask, Xnew, Anew);
}